// Round 3
// baseline (3182.140 us; speedup 1.0000x reference)
//
#include <hip/hip_runtime.h>
#include <hip/hip_bf16.h>

typedef __bf16 bf16;
typedef __attribute__((ext_vector_type(8))) __bf16 bf16x8;
typedef __attribute__((ext_vector_type(4))) __bf16 bf16x4;
typedef __attribute__((ext_vector_type(4))) float f32x4;
typedef __attribute__((ext_vector_type(4))) unsigned int u32x4;

#define T_STEPS 512
#define NWG 256

// workspace byte offsets
#define WS_CNT   0          //   4096 B  uint flags[512]: [p*256 + cg*2 + wv], value = step+1
#define WS_H     4096       // 131072 B  h_glob: two buffers [2][32][1024] bf16
#define WS_BTOT  135168     //  16384 B  btot [4][1024] f32
#define WS_XBF   151552     // 16777216 B  Xbf [512][32][512] bf16
#define WS_BPACK 16928768   // 12582912 B  Bpack fragments
// total 29511680 B (~28.1 MB)

// ---------- pack X: Xbf[t][b][d] = bf16(X[b][t][d]) ----------
__global__ void k_xpack(const float* __restrict__ X, bf16* __restrict__ Xbf) {
    int gid = blockIdx.x * 256 + threadIdx.x;   // 2,097,152 threads, 4 elems each
    int o = gid << 2;
    int d = o & 511, b = (o >> 9) & 31, t = o >> 14;
    const float4 v = *(const float4*)(X + (size_t)(b * 512 + t) * 512 + d);
    bf16x4 r;
    r.x = (bf16)v.x; r.y = (bf16)v.y; r.z = (bf16)v.z; r.w = (bf16)v.w;
    *(bf16x4*)(Xbf + (size_t)(t * 32 + b) * 512 + d) = r;
}

// ---------- pack weights into MFMA fragment order ----------
// layout: [cg 128][mk 48][nt 2][lane 64][j 8]
// value  = B[k][col],  k = mk*32 + (lane>>4)*8 + j,  col = nt*16 + (lane&15)
// col -> (g = col>>3, hl = col&7, h = cg*8+hl); k<1024 -> W_g[h][k], else U_g[h][k-1024]
__global__ void k_bpack(const float* __restrict__ W0, const float* __restrict__ W1,
                        const float* __restrict__ W2, const float* __restrict__ W3,
                        const float* __restrict__ U0, const float* __restrict__ U1,
                        const float* __restrict__ U2, const float* __restrict__ U3,
                        bf16* __restrict__ Bp) {
    int gid = blockIdx.x * 256 + threadIdx.x;   // 786,432 threads, one fragment (8 elems) each
    int lane = gid & 63; int idx = gid >> 6;
    int nt = idx & 1;  idx >>= 1;
    int mk = idx % 48; int cg = idx / 48;       // cg 0..127
    int kbase = mk * 32 + ((lane >> 4) << 3);
    int col = nt * 16 + (lane & 15);
    int g = col >> 3, hl = col & 7;
    int h = cg * 8 + hl;
    const float* Wg = (g == 0) ? W0 : (g == 1) ? W1 : (g == 2) ? W2 : W3;
    const float* Ug = (g == 0) ? U0 : (g == 1) ? U1 : (g == 2) ? U2 : U3;
    const float* src = (kbase < 1024) ? (Wg + (size_t)h * 1024 + kbase)
                                      : (Ug + (size_t)h * 512 + (kbase - 1024));
    float4 v0 = *(const float4*)(src);
    float4 v1 = *(const float4*)(src + 4);
    bf16x8 r;
    r[0] = (bf16)v0.x; r[1] = (bf16)v0.y; r[2] = (bf16)v0.z; r[3] = (bf16)v0.w;
    r[4] = (bf16)v1.x; r[5] = (bf16)v1.y; r[6] = (bf16)v1.z; r[7] = (bf16)v1.w;
    *(bf16x8*)(Bp + (size_t)gid * 8) = r;
}

// ---------- init: combined biases, zero both h buffers, zero flags ----------
__global__ void k_init(const float* bWf, const float* bUf, const float* bWi, const float* bUi,
                       const float* bWo, const float* bUo, const float* bWc, const float* bUc,
                       float* btot, bf16* hglob, unsigned* cnt) {
    int gid = blockIdx.x * 256 + threadIdx.x;   // 4096 threads
    int g = gid >> 10, h = gid & 1023;
    const float* bW = (g == 0) ? bWf : (g == 1) ? bWi : (g == 2) ? bWo : bWc;
    const float* bU = (g == 0) ? bUf : (g == 1) ? bUi : (g == 2) ? bUo : bUc;
    btot[gid] = bW[h] + bU[h];
    uint4 z; z.x = 0u; z.y = 0u; z.z = 0u; z.w = 0u;
    ((uint4*)hglob)[gid] = z;                   // 2 x 65536 B
    ((uint4*)hglob)[gid + 4096] = z;
    if (gid < 1024) cnt[gid] = 0u;
}

#define MFMA(a, b, c) __builtin_amdgcn_mfma_f32_16x16x32_bf16((a), (b), (c), 0, 0, 0)
#define BQ(i) __builtin_bit_cast(bf16x8, bqr[i])

// ---------- persistent scan kernel ----------
// 256 WGs x 256 threads. WG = (p = batch-half, cg = 8 h-indices x 4 gates = 32 cols).
// 4 waves each handle 8 h k-slices + 4 x k-slices; 2 N-tiles of 16 cols.
// Cross-WG exchange of h via sc0 sc1 stores/loads; flag-array barrier (no atomics).
__global__ __launch_bounds__(256, 1) void k_scan(
        const bf16* __restrict__ Bp, const bf16* __restrict__ Xbf,
        const float* __restrict__ btot, bf16* hglob, unsigned* cnt,
        float* __restrict__ out) {
    const int tid = threadIdx.x;
    const int lane = tid & 63, wid = tid >> 6;
    const int wg = blockIdx.x;
    const int p = wg & 1, cg = wg >> 1;

    // preload this wave's 24 B-fragments into registers (resident for whole scan)
    u32x4 bqr[24];
    {
#pragma unroll
        for (int i = 0; i < 24; ++i) {
            int mk = (i < 16) ? (wid * 8 + (i >> 1)) : (32 + wid * 4 + ((i - 16) >> 1));
            int nt = i & 1;
            const bf16* pfrag = Bp + ((((size_t)(cg * 48 + mk) * 2 + nt) * 64 + lane) << 3);
            asm volatile("global_load_dwordx4 %0, %1, off" : "=v"(bqr[i]) : "v"(pfrag));
        }
        asm volatile("s_waitcnt vmcnt(0)" ::: "memory");
        __builtin_amdgcn_sched_barrier(0);
    }

    const int arow = (lane & 15) + p * 16;        // batch row for A fragments
    const int koff = (lane >> 4) << 3;

    // elementwise thread mapping: tid<128, ehl = tid&7 (lane bits 0-2 -> shfl-packable)
    const bool ew = tid < 128;
    const int erow = (tid >> 3) & 15;             // wave0: rows 0..7, wave1: rows 8..15
    const int ehl = tid & 7;
    const int hgl = cg * 8 + ehl;
    float bias0 = 0.f, bias1 = 0.f, bias2 = 0.f, bias3 = 0.f;
    if (ew) {
        bias0 = btot[hgl];
        bias1 = btot[1024 + hgl];
        bias2 = btot[2048 + hgl];
        bias3 = btot[3072 + hgl];
    }
    const int b_glob = p * 16 + erow;
    float* outp = out + (size_t)b_glob * 512 * 1024 + hgl;
    bf16* hrow = hglob + b_glob * 1024 + cg * 8;  // packed 16B store base (ehl==0)
    float cst = 0.f;

    __shared__ float part[2][4][2][64][5];        // double-buffered, padded stride 5

    unsigned* flags = cnt;                         // 512 entries
    const unsigned* fpoll = flags + p * 256 + (lane << 2);

    for (int t = 0; t < T_STEPS; ++t) {
        // ---- phase A: x-projection part for step t (independent of h) ----
        f32x4 acc0 = {0.f, 0.f, 0.f, 0.f};
        f32x4 acc1 = {0.f, 0.f, 0.f, 0.f};
        {
            const bf16* xb = Xbf + ((size_t)(t * 32 + arow) << 9) + koff;
#pragma unroll
            for (int m = 0; m < 4; ++m) {
                bf16x8 a = *(const bf16x8*)(xb + ((wid * 4 + m) << 5));
                acc0 = MFMA(a, BQ(16 + 2 * m), acc0);
                acc1 = MFMA(a, BQ(17 + 2 * m), acc1);
            }
        }
        __builtin_amdgcn_sched_barrier(0);

        // ---- wait for h(t): poll 256 flags with one dwordx4 per lane ----
        if (t > 0) {
            const unsigned tgt = (unsigned)t;
            while (true) {
                u32x4 f;
                asm volatile("global_load_dwordx4 %0, %1, off sc0 sc1"
                             : "=v"(f) : "v"(fpoll) : "memory");
                asm volatile("s_waitcnt vmcnt(0)" ::: "memory");
                int ok = (f.x >= tgt) && (f.y >= tgt) && (f.z >= tgt) && (f.w >= tgt);
                if (__all(ok)) break;
            }
        }

        // ---- phase B: recurrent part; h loads bypass caches (coherent point) ----
        {
            const bf16* hbuf = hglob + ((size_t)(t & 1) << 15) + arow * 1024 + koff;
            u32x4 av[8];
#pragma unroll
            for (int m = 0; m < 8; ++m) {
                const bf16* ph = hbuf + ((wid * 8 + m) << 5);
                asm volatile("global_load_dwordx4 %0, %1, off sc0 sc1"
                             : "=v"(av[m]) : "v"(ph) : "memory");
            }
            asm volatile("s_waitcnt vmcnt(0)" ::: "memory");
            __builtin_amdgcn_sched_barrier(0);
#pragma unroll
            for (int m = 0; m < 8; ++m) {
                bf16x8 a = __builtin_bit_cast(bf16x8, av[m]);
                acc0 = MFMA(a, BQ(2 * m), acc0);
                acc1 = MFMA(a, BQ(2 * m + 1), acc1);
            }
        }
        {
            float* pp = &part[t & 1][wid][0][lane][0];
            pp[0] = acc0.x; pp[1] = acc0.y; pp[2] = acc0.z; pp[3] = acc0.w;
            float* pq = &part[t & 1][wid][1][lane][0];
            pq[0] = acc1.x; pq[1] = acc1.y; pq[2] = acc1.z; pq[3] = acc1.w;
        }
        __syncthreads();

        if (ew) {
            const int li0 = ((erow >> 2) << 4) | ehl;   // C/D: col=lane&15, row=(lane>>4)*4+reg
            const int li1 = li0 | 8;
            const int reg = erow & 3;
            const float (*pt)[2][64][5] = part[t & 1];
            float a0 = bias0, a1 = bias1, a2 = bias2, a3 = bias3;
#pragma unroll
            for (int w = 0; w < 4; ++w) {
                a0 += pt[w][0][li0][reg];
                a1 += pt[w][0][li1][reg];
                a2 += pt[w][1][li0][reg];
                a3 += pt[w][1][li1][reg];
            }
            float f  = 1.f / (1.f + __expf(-a0));
            float i  = 1.f / (1.f + __expf(-a1));
            float o  = 1.f / (1.f + __expf(-a2));
            float cb = 2.f / (1.f + __expf(-2.f * a3)) - 1.f;
            cst = f * cst + i * cb;
            float th = 2.f / (1.f + __expf(-2.f * cst)) - 1.f;
            float hv = o * th;

            // pack 8 bf16 (ehl 0..7, same row) into one 16B store via shfl_xor
            bf16 hb16 = (bf16)hv;
            unsigned hv32 = (unsigned)__builtin_bit_cast(unsigned short, hb16);
            unsigned w0 = hv32 << ((tid & 1) << 4);
            w0 |= (unsigned)__shfl_xor((int)w0, 1, 64);
            unsigned x2 = (unsigned)__shfl_xor((int)w0, 2, 64);
            unsigned lo2 = (tid & 2) ? x2 : w0;
            unsigned hi2 = (tid & 2) ? w0 : x2;
            unsigned xl = (unsigned)__shfl_xor((int)lo2, 4, 64);
            unsigned xh = (unsigned)__shfl_xor((int)hi2, 4, 64);
            u32x4 pk;
            if (tid & 4) { pk.x = xl;  pk.y = xh;  pk.z = lo2; pk.w = hi2; }
            else         { pk.x = lo2; pk.y = hi2; pk.z = xl;  pk.w = xh; }
            if (ehl == 0) {
                bf16* hst = hrow + (((t + 1) & 1) << 15);
                asm volatile("global_store_dwordx4 %0, %1, off sc0 sc1"
                             :: "v"(hst), "v"(pk) : "memory");
            }
            outp[(size_t)t << 10] = hv;                 // output (fp32, cached)
            asm volatile("s_waitcnt vmcnt(0)" ::: "memory");   // h stores ack'd at LLC
            if ((tid & 63) == 0) {                      // one flag store per ew wave
                unsigned* fl = flags + p * 256 + cg * 2 + (tid >> 6);
                unsigned v = (unsigned)(t + 1);
                asm volatile("global_store_dword %0, %1, off sc0 sc1"
                             :: "v"(fl), "v"(v) : "memory");
            }
        }
        // no trailing barrier: waves 2,3 run ahead into step t+1 (part is double-buffered)
    }
}

extern "C" void kernel_launch(void* const* d_in, const int* in_sizes, int n_in,
                              void* d_out, int out_size, void* d_ws, size_t ws_size,
                              hipStream_t stream) {
    const float* X   = (const float*)d_in[0];
    const float* Wf  = (const float*)d_in[1];
    const float* bWf = (const float*)d_in[2];
    const float* Uf  = (const float*)d_in[3];
    const float* bUf = (const float*)d_in[4];
    const float* Wi  = (const float*)d_in[5];
    const float* bWi = (const float*)d_in[6];
    const float* Ui  = (const float*)d_in[7];
    const float* bUi = (const float*)d_in[8];
    const float* Wo  = (const float*)d_in[9];
    const float* bWo = (const float*)d_in[10];
    const float* Uo  = (const float*)d_in[11];
    const float* bUo = (const float*)d_in[12];
    const float* Wc  = (const float*)d_in[13];
    const float* bWc = (const float*)d_in[14];
    const float* Uc  = (const float*)d_in[15];
    const float* bUc = (const float*)d_in[16];

    char* ws = (char*)d_ws;
    unsigned* cnt = (unsigned*)(ws + WS_CNT);
    bf16* hglob   = (bf16*)(ws + WS_H);
    float* btot   = (float*)(ws + WS_BTOT);
    bf16* Xbf     = (bf16*)(ws + WS_XBF);
    bf16* Bp      = (bf16*)(ws + WS_BPACK);
    float* out    = (float*)d_out;

    hipLaunchKernelGGL(k_init, dim3(16), dim3(256), 0, stream,
                       bWf, bUf, bWi, bUi, bWo, bUo, bWc, bUc, btot, hglob, cnt);
    hipLaunchKernelGGL(k_xpack, dim3(8192), dim3(256), 0, stream, X, Xbf);
    hipLaunchKernelGGL(k_bpack, dim3(3072), dim3(256), 0, stream,
                       Wf, Wi, Wo, Wc, Uf, Ui, Uo, Uc, Bp);
    hipLaunchKernelGGL(k_scan, dim3(NWG), dim3(256), 0, stream,
                       Bp, Xbf, btot, hglob, cnt, out);
}

// Round 4
// 2839.696 us; speedup vs baseline: 1.1206x; 1.1206x over previous
//
#include <hip/hip_runtime.h>
#include <hip/hip_bf16.h>

typedef __bf16 bf16;
typedef __attribute__((ext_vector_type(8))) __bf16 bf16x8;
typedef __attribute__((ext_vector_type(4))) __bf16 bf16x4;
typedef __attribute__((ext_vector_type(4))) float f32x4;
typedef __attribute__((ext_vector_type(4))) unsigned int u32x4;

#define T_STEPS 512
#define NWG 256

// workspace byte offsets
#define WS_CNT   0          //   4096 B  uint flags[512]: [p*256 + cg*2 + wv], value = step+1
#define WS_H     4096       // 131072 B  h_glob: two buffers [2][32][1024] bf16
#define WS_BTOT  135168     //  16384 B  btot [4][1024] f32
#define WS_XBF   151552     // 16777216 B  Xbf [512][32][512] bf16
#define WS_BPACK 16928768   // 12582912 B  Bpack fragments
// total 29511680 B (~28.1 MB)

// ---------- pack X: Xbf[t][b][d] = bf16(X[b][t][d]) ----------
__global__ void k_xpack(const float* __restrict__ X, bf16* __restrict__ Xbf) {
    int gid = blockIdx.x * 256 + threadIdx.x;   // 2,097,152 threads, 4 elems each
    int o = gid << 2;
    int d = o & 511, b = (o >> 9) & 31, t = o >> 14;
    const float4 v = *(const float4*)(X + (size_t)(b * 512 + t) * 512 + d);
    bf16x4 r;
    r.x = (bf16)v.x; r.y = (bf16)v.y; r.z = (bf16)v.z; r.w = (bf16)v.w;
    *(bf16x4*)(Xbf + (size_t)(t * 32 + b) * 512 + d) = r;
}

// ---------- pack weights into MFMA fragment order ----------
// layout: [cg 128][mk 48][nt 2][lane 64][j 8]
// value  = B[k][col],  k = mk*32 + (lane>>4)*8 + j,  col = nt*16 + (lane&15)
// col -> (g = col>>3, hl = col&7, h = cg*8+hl); k<1024 -> W_g[h][k], else U_g[h][k-1024]
__global__ void k_bpack(const float* __restrict__ W0, const float* __restrict__ W1,
                        const float* __restrict__ W2, const float* __restrict__ W3,
                        const float* __restrict__ U0, const float* __restrict__ U1,
                        const float* __restrict__ U2, const float* __restrict__ U3,
                        bf16* __restrict__ Bp) {
    int gid = blockIdx.x * 256 + threadIdx.x;   // 786,432 threads, one fragment (8 elems) each
    int lane = gid & 63; int idx = gid >> 6;
    int nt = idx & 1;  idx >>= 1;
    int mk = idx % 48; int cg = idx / 48;       // cg 0..127
    int kbase = mk * 32 + ((lane >> 4) << 3);
    int col = nt * 16 + (lane & 15);
    int g = col >> 3, hl = col & 7;
    int h = cg * 8 + hl;
    const float* Wg = (g == 0) ? W0 : (g == 1) ? W1 : (g == 2) ? W2 : W3;
    const float* Ug = (g == 0) ? U0 : (g == 1) ? U1 : (g == 2) ? U2 : U3;
    const float* src = (kbase < 1024) ? (Wg + (size_t)h * 1024 + kbase)
                                      : (Ug + (size_t)h * 512 + (kbase - 1024));
    float4 v0 = *(const float4*)(src);
    float4 v1 = *(const float4*)(src + 4);
    bf16x8 r;
    r[0] = (bf16)v0.x; r[1] = (bf16)v0.y; r[2] = (bf16)v0.z; r[3] = (bf16)v0.w;
    r[4] = (bf16)v1.x; r[5] = (bf16)v1.y; r[6] = (bf16)v1.z; r[7] = (bf16)v1.w;
    *(bf16x8*)(Bp + (size_t)gid * 8) = r;
}

// ---------- init: combined biases, zero both h buffers, zero flags ----------
__global__ void k_init(const float* bWf, const float* bUf, const float* bWi, const float* bUi,
                       const float* bWo, const float* bUo, const float* bWc, const float* bUc,
                       float* btot, bf16* hglob, unsigned* cnt) {
    int gid = blockIdx.x * 256 + threadIdx.x;   // 4096 threads
    int g = gid >> 10, h = gid & 1023;
    const float* bW = (g == 0) ? bWf : (g == 1) ? bWi : (g == 2) ? bWo : bWc;
    const float* bU = (g == 0) ? bUf : (g == 1) ? bUi : (g == 2) ? bUo : bUc;
    btot[gid] = bW[h] + bU[h];
    uint4 z; z.x = 0u; z.y = 0u; z.z = 0u; z.w = 0u;
    ((uint4*)hglob)[gid] = z;                   // 2 x 65536 B
    ((uint4*)hglob)[gid + 4096] = z;
    if (gid < 1024) cnt[gid] = 0u;
}

#define MFMA(a, b, c) __builtin_amdgcn_mfma_f32_16x16x32_bf16((a), (b), (c), 0, 0, 0)
#define BQ(i) __builtin_bit_cast(bf16x8, bqr[i])

// ---------- persistent scan kernel ----------
// 256 WGs x 256 threads. WG = (p = batch-half, cg = 8 h-indices x 4 gates = 32 cols).
// 4 waves each handle 8 h k-slices + 4 x k-slices; 2 N-tiles of 16 cols.
// Roles: wave 0 = flag poller, waves 2,3 = elementwise/producers.
// Cross-WG exchange of h via sc0 sc1 stores/loads; flag-array barrier (no atomics).
__global__ __launch_bounds__(256, 1) void k_scan(
        const bf16* __restrict__ Bp, const bf16* __restrict__ Xbf,
        const float* __restrict__ btot, bf16* hglob, unsigned* cnt,
        float* __restrict__ out) {
    const int tid = threadIdx.x;
    const int lane = tid & 63, wid = tid >> 6;
    const int wg = blockIdx.x;
    const int p = wg & 1, cg = wg >> 1;

    // preload this wave's 24 B-fragments into registers (resident for whole scan)
    u32x4 bqr[24];
    {
#pragma unroll
        for (int i = 0; i < 24; ++i) {
            int mk = (i < 16) ? (wid * 8 + (i >> 1)) : (32 + wid * 4 + ((i - 16) >> 1));
            int nt = i & 1;
            const bf16* pfrag = Bp + ((((size_t)(cg * 48 + mk) * 2 + nt) * 64 + lane) << 3);
            asm volatile("global_load_dwordx4 %0, %1, off" : "=v"(bqr[i]) : "v"(pfrag));
        }
        asm volatile("s_waitcnt vmcnt(0)" ::: "memory");
        __builtin_amdgcn_sched_barrier(0);
    }

    const int arow = (lane & 15) + p * 16;        // batch row for A fragments
    const int koff = (lane >> 4) << 3;

    // elementwise threads: waves 2,3 (tid >= 128); e in 0..127
    const bool ew = tid >= 128;
    const int e = tid & 127;
    const int erow = e >> 3;                      // wave2: rows 0..7, wave3: rows 8..15
    const int ehl = e & 7;
    const int hgl = cg * 8 + ehl;
    float bias0 = 0.f, bias1 = 0.f, bias2 = 0.f, bias3 = 0.f;
    if (ew) {
        bias0 = btot[hgl];
        bias1 = btot[1024 + hgl];
        bias2 = btot[2048 + hgl];
        bias3 = btot[3072 + hgl];
    }
    const int b_glob = p * 16 + erow;
    float* outp = out + (size_t)b_glob * 512 * 1024 + hgl;
    bf16* hrow = hglob + b_glob * 1024 + cg * 8;  // packed 16B store base (ehl==0)
    float cst = 0.f;

    __shared__ float part[2][4][2][64][5];        // double-buffered, padded stride 5

    unsigned* flags = cnt;                         // 512 entries
    const unsigned* fpoll = flags + p * 256 + (lane << 2);

    for (int t = 0; t < T_STEPS; ++t) {
        // ---- phase A: x-projection part for step t (independent of h) ----
        f32x4 acc0 = {0.f, 0.f, 0.f, 0.f};
        f32x4 acc1 = {0.f, 0.f, 0.f, 0.f};
        {
            const bf16* xb = Xbf + ((size_t)(t * 32 + arow) << 9) + koff;
#pragma unroll
            for (int m = 0; m < 4; ++m) {
                bf16x8 a = *(const bf16x8*)(xb + ((wid * 4 + m) << 5));
                acc0 = MFMA(a, BQ(16 + 2 * m), acc0);
                acc1 = MFMA(a, BQ(17 + 2 * m), acc1);
            }
        }

        // ---- wave 0 polls the 256 same-half flags; others wait at the barrier ----
        if (t > 0 && tid < 64) {
            const unsigned tgt = (unsigned)t;
            while (true) {
                u32x4 f;
                asm volatile("global_load_dwordx4 %0, %1, off sc0 sc1"
                             : "=v"(f) : "v"(fpoll) : "memory");
                asm volatile("s_waitcnt vmcnt(0)" ::: "memory");
                int ok = (f.x >= tgt) && (f.y >= tgt) && (f.z >= tgt) && (f.w >= tgt);
                if (__all(ok)) break;
            }
        }
        __syncthreads();                          // barrier1: h(t) globally visible

        // ---- phase B: recurrent part; h loads bypass caches (coherent point) ----
        {
            const bf16* hbuf = hglob + ((size_t)(t & 1) << 15) + arow * 1024 + koff;
            u32x4 av[8];
#pragma unroll
            for (int m = 0; m < 8; ++m) {
                const bf16* ph = hbuf + ((wid * 8 + m) << 5);
                asm volatile("global_load_dwordx4 %0, %1, off sc0 sc1"
                             : "=v"(av[m]) : "v"(ph) : "memory");
            }
            asm volatile("s_waitcnt vmcnt(0)" ::: "memory");
            __builtin_amdgcn_sched_barrier(0);
#pragma unroll
            for (int m = 0; m < 8; ++m) {
                bf16x8 a = __builtin_bit_cast(bf16x8, av[m]);
                acc0 = MFMA(a, BQ(2 * m), acc0);
                acc1 = MFMA(a, BQ(2 * m + 1), acc1);
            }
        }
        {
            float* pp = &part[t & 1][wid][0][lane][0];
            pp[0] = acc0.x; pp[1] = acc0.y; pp[2] = acc0.z; pp[3] = acc0.w;
            float* pq = &part[t & 1][wid][1][lane][0];
            pq[0] = acc1.x; pq[1] = acc1.y; pq[2] = acc1.z; pq[3] = acc1.w;
        }
        __syncthreads();                          // barrier2: partials ready

        if (ew) {
            const int li0 = ((erow >> 2) << 4) | ehl;   // C/D: col=lane&15, row=(lane>>4)*4+reg
            const int li1 = li0 | 8;
            const int reg = erow & 3;
            const float (*pt)[2][64][5] = part[t & 1];
            float a0 = bias0, a1 = bias1, a2 = bias2, a3 = bias3;
#pragma unroll
            for (int w = 0; w < 4; ++w) {
                a0 += pt[w][0][li0][reg];
                a1 += pt[w][0][li1][reg];
                a2 += pt[w][1][li0][reg];
                a3 += pt[w][1][li1][reg];
            }
            float f  = 1.f / (1.f + __expf(-a0));
            float i  = 1.f / (1.f + __expf(-a1));
            float o  = 1.f / (1.f + __expf(-a2));
            float cb = 2.f / (1.f + __expf(-2.f * a3)) - 1.f;
            cst = f * cst + i * cb;
            float th = 2.f / (1.f + __expf(-2.f * cst)) - 1.f;
            float hv = o * th;

            // pack 8 bf16 (ehl 0..7, same row) into one 16B store via shfl_xor
            bf16 hb16 = (bf16)hv;
            unsigned hv32 = (unsigned)__builtin_bit_cast(unsigned short, hb16);
            unsigned w0 = hv32 << ((tid & 1) << 4);
            w0 |= (unsigned)__shfl_xor((int)w0, 1, 64);
            unsigned x2 = (unsigned)__shfl_xor((int)w0, 2, 64);
            unsigned lo2 = (tid & 2) ? x2 : w0;
            unsigned hi2 = (tid & 2) ? w0 : x2;
            unsigned xl = (unsigned)__shfl_xor((int)lo2, 4, 64);
            unsigned xh = (unsigned)__shfl_xor((int)hi2, 4, 64);
            u32x4 pk;
            if (tid & 4) { pk.x = xl;  pk.y = xh;  pk.z = lo2; pk.w = hi2; }
            else         { pk.x = lo2; pk.y = hi2; pk.z = xl;  pk.w = xh; }
            if (ehl == 0) {
                bf16* hst = hrow + (((t + 1) & 1) << 15);
                asm volatile("global_store_dwordx4 %0, %1, off sc0 sc1"
                             :: "v"(hst), "v"(pk) : "memory");
            }
            asm volatile("s_waitcnt vmcnt(0)" ::: "memory");   // h stores ack'd at LLC
            if ((tid & 63) == 0) {                             // one flag store per ew wave
                unsigned* fl = flags + p * 256 + cg * 2 + ((tid >> 6) & 1);
                unsigned v = (unsigned)(t + 1);
                asm volatile("global_store_dword %0, %1, off sc0 sc1"
                             :: "v"(fl), "v"(v) : "memory");
            }
            outp[(size_t)t << 10] = hv;           // output (fp32, cached, off critical path)
        }
        // waves 0,1 fall through to t+1 phase A immediately (part is double-buffered)
    }
}

extern "C" void kernel_launch(void* const* d_in, const int* in_sizes, int n_in,
                              void* d_out, int out_size, void* d_ws, size_t ws_size,
                              hipStream_t stream) {
    const float* X   = (const float*)d_in[0];
    const float* Wf  = (const float*)d_in[1];
    const float* bWf = (const float*)d_in[2];
    const float* Uf  = (const float*)d_in[3];
    const float* bUf = (const float*)d_in[4];
    const float* Wi  = (const float*)d_in[5];
    const float* bWi = (const float*)d_in[6];
    const float* Ui  = (const float*)d_in[7];
    const float* bUi = (const float*)d_in[8];
    const float* Wo  = (const float*)d_in[9];
    const float* bWo = (const float*)d_in[10];
    const float* Uo  = (const float*)d_in[11];
    const float* bUo = (const float*)d_in[12];
    const float* Wc  = (const float*)d_in[13];
    const float* bWc = (const float*)d_in[14];
    const float* Uc  = (const float*)d_in[15];
    const float* bUc = (const float*)d_in[16];

    char* ws = (char*)d_ws;
    unsigned* cnt = (unsigned*)(ws + WS_CNT);
    bf16* hglob   = (bf16*)(ws + WS_H);
    float* btot   = (float*)(ws + WS_BTOT);
    bf16* Xbf     = (bf16*)(ws + WS_XBF);
    bf16* Bp      = (bf16*)(ws + WS_BPACK);
    float* out    = (float*)d_out;

    hipLaunchKernelGGL(k_init, dim3(16), dim3(256), 0, stream,
                       bWf, bUf, bWi, bUi, bWo, bUo, bWc, bUc, btot, hglob, cnt);
    hipLaunchKernelGGL(k_xpack, dim3(8192), dim3(256), 0, stream, X, Xbf);
    hipLaunchKernelGGL(k_bpack, dim3(3072), dim3(256), 0, stream,
                       Wf, Wi, Wo, Wc, Uf, Ui, Uo, Uc, Bp);
    hipLaunchKernelGGL(k_scan, dim3(NWG), dim3(256), 0, stream,
                       Bp, Xbf, btot, hglob, cnt, out);
}

// Round 5
// 2259.989 us; speedup vs baseline: 1.4080x; 1.2565x over previous
//
#include <hip/hip_runtime.h>
#include <hip/hip_bf16.h>

typedef __bf16 bf16;
typedef __attribute__((ext_vector_type(8))) __bf16 bf16x8;
typedef __attribute__((ext_vector_type(4))) __bf16 bf16x4;
typedef __attribute__((ext_vector_type(4))) float f32x4;
typedef __attribute__((ext_vector_type(4))) unsigned int u32x4;

#define T_STEPS 512
#define NWG 128

// workspace byte offsets
#define WS_CNT   0          //  16384 B  uint flags[128], one per 128B line: cnt[wg*32]
#define WS_H     16384      // 131072 B  h_glob: two buffers [2][32][1024] bf16
#define WS_BTOT  147456     //  16384 B  btot [4][1024] f32
#define WS_XBF   163840     // 16777216 B  Xbf [512][32][512] bf16
#define WS_BPACK 16941056   // 12582912 B  Bpack fragments
// total 29523968 B (~28.2 MB)

// ---------- pack X: Xbf[t][b][d] = bf16(X[b][t][d]) ----------
__global__ void k_xpack(const float* __restrict__ X, bf16* __restrict__ Xbf) {
    int gid = blockIdx.x * 256 + threadIdx.x;   // 2,097,152 threads, 4 elems each
    int o = gid << 2;
    int d = o & 511, b = (o >> 9) & 31, t = o >> 14;
    const float4 v = *(const float4*)(X + (size_t)(b * 512 + t) * 512 + d);
    bf16x4 r;
    r.x = (bf16)v.x; r.y = (bf16)v.y; r.z = (bf16)v.z; r.w = (bf16)v.w;
    *(bf16x4*)(Xbf + (size_t)(t * 32 + b) * 512 + d) = r;
}

// ---------- pack weights into MFMA fragment order ----------
// layout: [cg 128][mk 48][nt 2][lane 64][j 8]
// value  = B[k][col],  k = mk*32 + (lane>>4)*8 + j,  col = nt*16 + (lane&15)
// col -> (g = col>>3, hl = col&7, h = cg*8+hl); k<1024 -> W_g[h][k], else U_g[h][k-1024]
__global__ void k_bpack(const float* __restrict__ W0, const float* __restrict__ W1,
                        const float* __restrict__ W2, const float* __restrict__ W3,
                        const float* __restrict__ U0, const float* __restrict__ U1,
                        const float* __restrict__ U2, const float* __restrict__ U3,
                        bf16* __restrict__ Bp) {
    int gid = blockIdx.x * 256 + threadIdx.x;   // 786,432 threads, one fragment (8 elems) each
    int lane = gid & 63; int idx = gid >> 6;
    int nt = idx & 1;  idx >>= 1;
    int mk = idx % 48; int cg = idx / 48;       // cg 0..127
    int kbase = mk * 32 + ((lane >> 4) << 3);
    int col = nt * 16 + (lane & 15);
    int g = col >> 3, hl = col & 7;
    int h = cg * 8 + hl;
    const float* Wg = (g == 0) ? W0 : (g == 1) ? W1 : (g == 2) ? W2 : W3;
    const float* Ug = (g == 0) ? U0 : (g == 1) ? U1 : (g == 2) ? U2 : U3;
    const float* src = (kbase < 1024) ? (Wg + (size_t)h * 1024 + kbase)
                                      : (Ug + (size_t)h * 512 + (kbase - 1024));
    float4 v0 = *(const float4*)(src);
    float4 v1 = *(const float4*)(src + 4);
    bf16x8 r;
    r[0] = (bf16)v0.x; r[1] = (bf16)v0.y; r[2] = (bf16)v0.z; r[3] = (bf16)v0.w;
    r[4] = (bf16)v1.x; r[5] = (bf16)v1.y; r[6] = (bf16)v1.z; r[7] = (bf16)v1.w;
    *(bf16x8*)(Bp + (size_t)gid * 8) = r;
}

// ---------- init: combined biases, zero both h buffers, zero flags ----------
__global__ void k_init(const float* bWf, const float* bUf, const float* bWi, const float* bUi,
                       const float* bWo, const float* bUo, const float* bWc, const float* bUc,
                       float* btot, bf16* hglob, unsigned* cnt) {
    int gid = blockIdx.x * 256 + threadIdx.x;   // 4096 threads
    int g = gid >> 10, h = gid & 1023;
    const float* bW = (g == 0) ? bWf : (g == 1) ? bWi : (g == 2) ? bWo : bWc;
    const float* bU = (g == 0) ? bUf : (g == 1) ? bUi : (g == 2) ? bUo : bUc;
    btot[gid] = bW[h] + bU[h];
    uint4 z; z.x = 0u; z.y = 0u; z.z = 0u; z.w = 0u;
    ((uint4*)hglob)[gid] = z;                   // 2 x 65536 B
    ((uint4*)hglob)[gid + 4096] = z;
    cnt[gid] = 0u;                              // 16 KB flag region
}

#define MFMA(a, b, c) __builtin_amdgcn_mfma_f32_16x16x32_bf16((a), (b), (c), 0, 0, 0)
#define BQ(i) __builtin_bit_cast(bf16x8, bqr[i])

// ---------- persistent scan kernel ----------
// 128 WGs x 512 threads = 2 quads (p = quad = batch-half), cg = blockIdx (8 h x 4 gates).
// Per quad: 4 waves x (8 h k-slices + 4 x k-slices), 2 N-tiles of 16 cols.
// Barrier: per-WG flag on own 128B line after all 4 ew waves ack h; wave 0 polls all
// 128 flag lines with 1 request per line per round. All data via sc0 sc1 at LLC.
__global__ __launch_bounds__(512, 1) void k_scan(
        const bf16* __restrict__ Bp, const bf16* __restrict__ Xbf,
        const float* __restrict__ btot, bf16* hglob, unsigned* cnt,
        float* __restrict__ out) {
    const int tid = threadIdx.x;
    const int q = tid >> 8;                      // quad = batch-half p
    const int qtid = tid & 255;
    const int lane = tid & 63;
    const int wid = (tid >> 6) & 3;              // wave within quad
    const int p = q;
    const int cg = blockIdx.x;                   // 0..127

    // preload this wave's 24 B-fragments into registers (resident for whole scan)
    u32x4 bqr[24];
    {
#pragma unroll
        for (int i = 0; i < 24; ++i) {
            int mk = (i < 16) ? (wid * 8 + (i >> 1)) : (32 + wid * 4 + ((i - 16) >> 1));
            int nt = i & 1;
            const bf16* pfrag = Bp + ((((size_t)(cg * 48 + mk) * 2 + nt) * 64 + lane) << 3);
            asm volatile("global_load_dwordx4 %0, %1, off" : "=v"(bqr[i]) : "v"(pfrag));
        }
        asm volatile("s_waitcnt vmcnt(0)" ::: "memory");
        __builtin_amdgcn_sched_barrier(0);
    }

    const int arow = (lane & 15) + p * 16;        // batch row for A fragments
    const int koff = (lane >> 4) << 3;

    // elementwise threads: waves 2,3 of each quad; e in 0..127
    const bool ew = qtid >= 128;
    const int e = qtid & 127;
    const int erow = e >> 3;
    const int ehl = e & 7;
    const int hgl = cg * 8 + ehl;
    float bias0 = 0.f, bias1 = 0.f, bias2 = 0.f, bias3 = 0.f;
    if (ew) {
        bias0 = btot[hgl];
        bias1 = btot[1024 + hgl];
        bias2 = btot[2048 + hgl];
        bias3 = btot[3072 + hgl];
    }
    const int b_glob = p * 16 + erow;
    float* outp = out + (size_t)b_glob * 512 * 1024 + hgl;
    bf16* hrow = hglob + b_glob * 1024 + cg * 8;  // packed 16B store base (ehl==0)
    float cst = 0.f;

    __shared__ float part[2][2][4][2][64][5];     // [quad][buf][wid][nt][lane][reg]
    __shared__ unsigned ackcnt;
    if (tid == 0) ackcnt = 0u;
    __syncthreads();

    unsigned* flags = cnt;                         // flag for wg w at cnt[w*32]
    const unsigned* fp0 = cnt + (lane << 5);               // lines 0..63
    const unsigned* fp1 = cnt + ((64 + lane) << 5);        // lines 64..127

    for (int t = 0; t < T_STEPS; ++t) {
        // ---- phase A: x-projection part for step t (independent of h) ----
        f32x4 acc0 = {0.f, 0.f, 0.f, 0.f};
        f32x4 acc1 = {0.f, 0.f, 0.f, 0.f};
        {
            const bf16* xb = Xbf + ((size_t)(t * 32 + arow) << 9) + koff;
#pragma unroll
            for (int m = 0; m < 4; ++m) {
                bf16x8 a = *(const bf16x8*)(xb + ((wid * 4 + m) << 5));
                acc0 = MFMA(a, BQ(16 + 2 * m), acc0);
                acc1 = MFMA(a, BQ(17 + 2 * m), acc1);
            }
        }

        // ---- wave 0 polls all 128 flag lines: 1 request per line per round ----
        if (t > 0 && tid < 64) {
            const unsigned tgt = (unsigned)t;
            while (true) {
                unsigned f0, f1;
                asm volatile("global_load_dword %0, %2, off sc0 sc1\n\t"
                             "global_load_dword %1, %3, off sc0 sc1"
                             : "=v"(f0), "=v"(f1) : "v"(fp0), "v"(fp1) : "memory");
                asm volatile("s_waitcnt vmcnt(0)" ::: "memory");
                if (__all(f0 >= tgt && f1 >= tgt)) break;
            }
        }
        __syncthreads();                          // barrier1: h(t) globally visible

        // ---- phase B: recurrent part; h loads from LLC (coherent point) ----
        {
            const bf16* hbuf = hglob + ((size_t)(t & 1) << 15) + arow * 1024 + koff;
            u32x4 av[8];
#pragma unroll
            for (int m = 0; m < 8; ++m) {
                const bf16* ph = hbuf + ((wid * 8 + m) << 5);
                asm volatile("global_load_dwordx4 %0, %1, off sc0 sc1"
                             : "=v"(av[m]) : "v"(ph) : "memory");
            }
            asm volatile("s_waitcnt vmcnt(0)" ::: "memory");
            __builtin_amdgcn_sched_barrier(0);
#pragma unroll
            for (int m = 0; m < 8; ++m) {
                bf16x8 a = __builtin_bit_cast(bf16x8, av[m]);
                acc0 = MFMA(a, BQ(2 * m), acc0);
                acc1 = MFMA(a, BQ(2 * m + 1), acc1);
            }
        }
        {
            float* pp = &part[q][t & 1][wid][0][lane][0];
            pp[0] = acc0.x; pp[1] = acc0.y; pp[2] = acc0.z; pp[3] = acc0.w;
            float* pq = &part[q][t & 1][wid][1][lane][0];
            pq[0] = acc1.x; pq[1] = acc1.y; pq[2] = acc1.z; pq[3] = acc1.w;
        }
        __syncthreads();                          // barrier2: partials ready

        if (ew) {
            const int li0 = ((erow >> 2) << 4) | ehl;   // C/D: col=lane&15, row=(lane>>4)*4+reg
            const int li1 = li0 | 8;
            const int reg = erow & 3;
            const float (*pt)[2][64][5] = part[q][t & 1];
            float a0 = bias0, a1 = bias1, a2 = bias2, a3 = bias3;
#pragma unroll
            for (int w = 0; w < 4; ++w) {
                a0 += pt[w][0][li0][reg];
                a1 += pt[w][0][li1][reg];
                a2 += pt[w][1][li0][reg];
                a3 += pt[w][1][li1][reg];
            }
            float f  = 1.f / (1.f + __expf(-a0));
            float i  = 1.f / (1.f + __expf(-a1));
            float o  = 1.f / (1.f + __expf(-a2));
            float cb = 2.f / (1.f + __expf(-2.f * a3)) - 1.f;
            cst = f * cst + i * cb;
            float th = 2.f / (1.f + __expf(-2.f * cst)) - 1.f;
            float hv = o * th;

            // pack 8 bf16 (ehl 0..7, same row) into one 16B store via shfl_xor
            bf16 hb16 = (bf16)hv;
            unsigned hv32 = (unsigned)__builtin_bit_cast(unsigned short, hb16);
            unsigned w0 = hv32 << ((lane & 1) << 4);
            w0 |= (unsigned)__shfl_xor((int)w0, 1, 64);
            unsigned x2 = (unsigned)__shfl_xor((int)w0, 2, 64);
            unsigned lo2 = (lane & 2) ? x2 : w0;
            unsigned hi2 = (lane & 2) ? w0 : x2;
            unsigned xl = (unsigned)__shfl_xor((int)lo2, 4, 64);
            unsigned xh = (unsigned)__shfl_xor((int)hi2, 4, 64);
            u32x4 pk;
            if (lane & 4) { pk.x = xl;  pk.y = xh;  pk.z = lo2; pk.w = hi2; }
            else          { pk.x = lo2; pk.y = hi2; pk.z = xl;  pk.w = xh; }
            if (ehl == 0) {
                bf16* hst = hrow + (((t + 1) & 1) << 15);
                asm volatile("global_store_dwordx4 %0, %1, off sc0 sc1"
                             :: "v"(hst), "v"(pk) : "memory");
            }
            asm volatile("s_waitcnt vmcnt(0)" ::: "memory");   // h stores ack'd at LLC
            if (lane == 0) {                      // 4 ew waves per WG count in via LDS
                unsigned old = atomicAdd(&ackcnt, 1u);
                if ((old & 3u) == 3u) {           // last of this step's four
                    unsigned* fl = flags + (blockIdx.x << 5);
                    unsigned v = (unsigned)(t + 1);
                    asm volatile("global_store_dword %0, %1, off sc0 sc1"
                                 :: "v"(fl), "v"(v) : "memory");
                }
            }
            outp[(size_t)t << 10] = hv;           // output (fp32, cached, off critical path)
        }
        // waves 0,1 of each quad fall through to t+1 phase A immediately
    }
}

extern "C" void kernel_launch(void* const* d_in, const int* in_sizes, int n_in,
                              void* d_out, int out_size, void* d_ws, size_t ws_size,
                              hipStream_t stream) {
    const float* X   = (const float*)d_in[0];
    const float* Wf  = (const float*)d_in[1];
    const float* bWf = (const float*)d_in[2];
    const float* Uf  = (const float*)d_in[3];
    const float* bUf = (const float*)d_in[4];
    const float* Wi  = (const float*)d_in[5];
    const float* bWi = (const float*)d_in[6];
    const float* Ui  = (const float*)d_in[7];
    const float* bUi = (const float*)d_in[8];
    const float* Wo  = (const float*)d_in[9];
    const float* bWo = (const float*)d_in[10];
    const float* Uo  = (const float*)d_in[11];
    const float* bUo = (const float*)d_in[12];
    const float* Wc  = (const float*)d_in[13];
    const float* bWc = (const float*)d_in[14];
    const float* Uc  = (const float*)d_in[15];
    const float* bUc = (const float*)d_in[16];

    char* ws = (char*)d_ws;
    unsigned* cnt = (unsigned*)(ws + WS_CNT);
    bf16* hglob   = (bf16*)(ws + WS_H);
    float* btot   = (float*)(ws + WS_BTOT);
    bf16* Xbf     = (bf16*)(ws + WS_XBF);
    bf16* Bp      = (bf16*)(ws + WS_BPACK);
    float* out    = (float*)d_out;

    hipLaunchKernelGGL(k_init, dim3(16), dim3(256), 0, stream,
                       bWf, bUf, bWi, bUi, bWo, bUo, bWc, bUc, btot, hglob, cnt);
    hipLaunchKernelGGL(k_xpack, dim3(8192), dim3(256), 0, stream, X, Xbf);
    hipLaunchKernelGGL(k_bpack, dim3(3072), dim3(256), 0, stream,
                       Wf, Wi, Wo, Wc, Uf, Ui, Uo, Uc, Bp);
    hipLaunchKernelGGL(k_scan, dim3(NWG), dim3(512), 0, stream,
                       Bp, Xbf, btot, hglob, cnt, out);
}